// Round 4
// baseline (1129.789 us; speedup 1.0000x reference)
//
#include <hip/hip_runtime.h>
#include <hip/hip_bf16.h>

// GraphSparseConvolution on MI355X.
// Round 3: (a) two-phase binned counting sort replaces the random 8B scatter
//     (phase A: coarse 256-row buckets with frontier-local writes; phase B:
//     per-bucket LDS counting sort emitting sorted records + row_start),
// (b) wave-per-row SpMM with 2 cols/lane and 4 gathers in flight,
// (c) h kept f16.  Fallback to atomic path if ws too small.

static constexpr int O_DIM = 128;
static constexpr float KEEP_INV = 1.0f / 0.9f;  // 1/keep_prob
static constexpr int BUCK_BINS = 256;           // rows per coarse bucket

using half_t = _Float16;
using half2_t = _Float16 __attribute__((ext_vector_type(2)));

// ---------------------------------------------------------------------------
// Detect how the harness materialized the bool keep_mask (int32/f32/uint8).
__global__ void detect_mask_kernel(const unsigned int* __restrict__ w, int nwords,
                                   int* __restrict__ flags) {
    __shared__ int sA[256];
    __shared__ int sB[256];
    int t = threadIdx.x;
    int violA = 0, violB = 0;
    for (int i = t; i < nwords; i += 256) {
        unsigned int x = w[i];
        violA |= (x > 1u) ? 1 : 0;
        violB |= (x != 0u && x != 0x3F800000u) ? 1 : 0;
    }
    sA[t] = violA; sB[t] = violB;
    __syncthreads();
    for (int s = 128; s > 0; s >>= 1) {
        if (t < s) { sA[t] |= sA[t + s]; sB[t] |= sB[t + s]; }
        __syncthreads();
    }
    if (t == 0) { flags[0] = sA[0]; flags[1] = sB[0]; }
}

// ---------------------------------------------------------------------------
// Coarse bucket histogram (LDS-aggregated). bin = row (X) or n_nodes+row (adj);
// bucket = bin >> 8.  nbuck <= 1024 assumed (guarded by caller).
__global__ __launch_bounds__(256) void count_buckets_kernel(
        const int* __restrict__ xr, int nnz_x,
        const int* __restrict__ ar, int nnz_a,
        int n_nodes, int nbuck, int* __restrict__ bcnt) {
    __shared__ int hist[1024];
    int t = threadIdx.x;
    for (int k = t; k < 1024; k += 256) hist[k] = 0;
    __syncthreads();
    int stride = gridDim.x * blockDim.x;
    int tot = nnz_x + nnz_a;
    for (int i = blockIdx.x * blockDim.x + t; i < tot; i += stride) {
        int bin = (i < nnz_x) ? xr[i] : (n_nodes + ar[i - nnz_x]);
        atomicAdd(&hist[bin >> 8], 1);
    }
    __syncthreads();
    for (int k = t; k < nbuck; k += 256) {
        int h = hist[k];
        if (h) atomicAdd(&bcnt[k], h);
    }
}

// ---------------------------------------------------------------------------
// Single-block exclusive scan of bucket counts (nb <= 1024).
// Writes buckS[0..nb], a cursor copy, and the global row_start sentinel.
__global__ __launch_bounds__(1024) void scan_buckets_kernel(
        const int* __restrict__ bcnt, int nb,
        int* __restrict__ buckS, int* __restrict__ buckCur,
        int* __restrict__ S_sentinel) {
    __shared__ int wsum[16];
    int t = threadIdx.x, lane = t & 63, wid = t >> 6;
    int v = (t < nb) ? bcnt[t] : 0;
    int s = v;
    #pragma unroll
    for (int d = 1; d < 64; d <<= 1) {
        int u = __shfl_up(s, d, 64);
        if (lane >= d) s += u;
    }
    if (lane == 63) wsum[wid] = s;
    __syncthreads();
    int woff = 0;
    for (int w = 0; w < wid; ++w) woff += wsum[w];
    int excl = woff + s - v;
    if (t < nb) { buckS[t] = excl; buckCur[t] = excl; }
    if (t == 1023) { buckS[nb] = woff + s; *S_sentinel = woff + s; }
}

// ---------------------------------------------------------------------------
// Phase A: scatter both matrices' edges into coarse bucket regions.
// Record: { key = (bin_local << 17) | col , val_bits }.  col < 2^17.
__global__ void binscat_kernel(const float* __restrict__ xv,
                               const int* __restrict__ xr,
                               const int* __restrict__ xc,
                               const void* __restrict__ mask,
                               const int* __restrict__ flags,
                               const float* __restrict__ av,
                               const int* __restrict__ ar,
                               const int* __restrict__ ac,
                               int nnz_x, int nnz_a, int n_nodes,
                               int* __restrict__ buckCur,
                               int2* __restrict__ rec) {
    int stride = gridDim.x * blockDim.x;
    int tot = nnz_x + nnz_a;
    int f0 = flags[0], f1 = flags[1];
    for (int i = blockIdx.x * blockDim.x + threadIdx.x; i < tot; i += stride) {
        int bin, col; float v;
        if (i < nnz_x) {
            bin = xr[i];
            col = xc[i];
            bool keep;
            if (f0 == 0)      keep = ((const int*)mask)[i] != 0;
            else if (f1 == 0) keep = ((const float*)mask)[i] != 0.0f;
            else              keep = ((const unsigned char*)mask)[i] != 0;
            v = keep ? xv[i] * KEEP_INV : 0.0f;
        } else {
            int e = i - nnz_x;
            bin = n_nodes + ar[e];
            col = ac[e];
            v = av[e];
        }
        int key = ((bin & (BUCK_BINS - 1)) << 17) | col;
        int pos = atomicAdd(&buckCur[bin >> 8], 1);
        rec[pos] = make_int2(key, __float_as_int(v));
    }
}

// ---------------------------------------------------------------------------
// Phase B: one block per bucket.  LDS counting sort over 256 local bins:
// hist -> scan (writes row_start S) -> rank & emit sorted (col,val) records.
__global__ __launch_bounds__(256) void bucket_sort_kernel(
        const int2* __restrict__ rec,
        const int* __restrict__ buckS,
        int ntot, int2* __restrict__ packed,
        int* __restrict__ S) {
    __shared__ int hist[256];
    __shared__ int cur[256];
    __shared__ int wsum[4];
    int bb = blockIdx.x, t = threadIdx.x;
    int start = buckS[bb], end = buckS[bb + 1];
    hist[t] = 0;
    __syncthreads();
    for (int i = start + t; i < end; i += 256) {
        unsigned k = (unsigned)rec[i].x;
        atomicAdd(&hist[k >> 17], 1);
    }
    __syncthreads();
    int v = hist[t];
    int lane = t & 63, wid = t >> 6;
    int s = v;
    #pragma unroll
    for (int d = 1; d < 64; d <<= 1) {
        int u = __shfl_up(s, d, 64);
        if (lane >= d) s += u;
    }
    if (lane == 63) wsum[wid] = s;
    __syncthreads();
    int woff = 0;
    for (int w = 0; w < wid; ++w) woff += wsum[w];
    int excl = woff + s - v;
    int binBase = bb << 8;
    if (binBase + t < ntot) S[binBase + t] = start + excl;
    cur[t] = start + excl;
    __syncthreads();
    for (int i = start + t; i < end; i += 256) {
        int2 e = rec[i];
        unsigned k = (unsigned)e.x;
        int pos = atomicAdd(&cur[k >> 17], 1);
        packed[pos] = make_int2((int)(k & 0x1FFFFu), e.y);
    }
}

// ---------------------------------------------------------------------------
// SpMM1: wave-per-row, 2 cols/lane, 4 gathers in flight. src = kernel (f32),
// dst = h (f16x2).
__global__ __launch_bounds__(256) void spmm1_wave_kernel(
        const int* __restrict__ S, const int2* __restrict__ packed,
        const float2* __restrict__ kern2, half2_t* __restrict__ h2,
        int n_rows) {
    int gid = blockIdx.x * 256 + threadIdx.x;
    int r = gid >> 6;
    if (r >= n_rows) return;
    int lane = gid & 63;
    int j = S[r], end = S[r + 1];
    float ax = 0.0f, ay = 0.0f;
    for (; j + 4 <= end; j += 4) {
        int2 e0 = packed[j], e1 = packed[j + 1], e2 = packed[j + 2], e3 = packed[j + 3];
        float2 w0 = kern2[e0.x * 64 + lane];
        float2 w1 = kern2[e1.x * 64 + lane];
        float2 w2 = kern2[e2.x * 64 + lane];
        float2 w3 = kern2[e3.x * 64 + lane];
        float v0 = __int_as_float(e0.y), v1 = __int_as_float(e1.y);
        float v2 = __int_as_float(e2.y), v3 = __int_as_float(e3.y);
        ax = fmaf(v0, w0.x, ax); ay = fmaf(v0, w0.y, ay);
        ax = fmaf(v1, w1.x, ax); ay = fmaf(v1, w1.y, ay);
        ax = fmaf(v2, w2.x, ax); ay = fmaf(v2, w2.y, ay);
        ax = fmaf(v3, w3.x, ax); ay = fmaf(v3, w3.y, ay);
    }
    for (; j < end; ++j) {
        int2 e = packed[j];
        float2 w = kern2[e.x * 64 + lane];
        float v = __int_as_float(e.y);
        ax = fmaf(v, w.x, ax); ay = fmaf(v, w.y, ay);
    }
    half2_t o; o.x = (half_t)ax; o.y = (half_t)ay;
    h2[r * 64 + lane] = o;
}

// SpMM2 + ReLU: wave-per-row, src = h (f16x2), dst = out (f32x2).
__global__ __launch_bounds__(256) void spmm2_wave_kernel(
        const int* __restrict__ S, const int2* __restrict__ packed,
        const half2_t* __restrict__ h2, float2* __restrict__ out2,
        int n_rows) {
    int gid = blockIdx.x * 256 + threadIdx.x;
    int r = gid >> 6;
    if (r >= n_rows) return;
    int lane = gid & 63;
    int j = S[r], end = S[r + 1];
    float ax = 0.0f, ay = 0.0f;
    for (; j + 4 <= end; j += 4) {
        int2 e0 = packed[j], e1 = packed[j + 1], e2 = packed[j + 2], e3 = packed[j + 3];
        half2_t w0 = h2[e0.x * 64 + lane];
        half2_t w1 = h2[e1.x * 64 + lane];
        half2_t w2 = h2[e2.x * 64 + lane];
        half2_t w3 = h2[e3.x * 64 + lane];
        float v0 = __int_as_float(e0.y), v1 = __int_as_float(e1.y);
        float v2 = __int_as_float(e2.y), v3 = __int_as_float(e3.y);
        ax = fmaf(v0, (float)w0.x, ax); ay = fmaf(v0, (float)w0.y, ay);
        ax = fmaf(v1, (float)w1.x, ax); ay = fmaf(v1, (float)w1.y, ay);
        ax = fmaf(v2, (float)w2.x, ax); ay = fmaf(v2, (float)w2.y, ay);
        ax = fmaf(v3, (float)w3.x, ax); ay = fmaf(v3, (float)w3.y, ay);
    }
    for (; j < end; ++j) {
        int2 e = packed[j];
        half2_t w = h2[e.x * 64 + lane];
        float v = __int_as_float(e.y);
        ax = fmaf(v, (float)w.x, ax); ay = fmaf(v, (float)w.y, ay);
    }
    out2[r * 64 + lane] = make_float2(fmaxf(ax, 0.0f), fmaxf(ay, 0.0f));
}

// ---------------------------------------------------------------------------
// Fallback atomic path (only if ws too small).
__global__ void spmm1_atomic_kernel(const float* __restrict__ xv,
                                    const int* __restrict__ xr,
                                    const int* __restrict__ xc,
                                    const void* __restrict__ mask,
                                    const float* __restrict__ kern,
                                    const int* __restrict__ flags,
                                    float* __restrict__ h, int nnz) {
    long long gid = (long long)blockIdx.x * blockDim.x + threadIdx.x;
    int e = (int)(gid >> 7);
    if (e >= nnz) return;
    int o = (int)(gid & 127);
    bool keep;
    if (flags[0] == 0)      keep = ((const int*)mask)[e] != 0;
    else if (flags[1] == 0) keep = ((const float*)mask)[e] != 0.0f;
    else                    keep = ((const unsigned char*)mask)[e] != 0;
    if (!keep) return;
    atomicAdd(&h[(long long)xr[e] * O_DIM + o], xv[e] * KEEP_INV * kern[xc[e] * O_DIM + o]);
}

__global__ void spmm2_atomic_kernel(const float* __restrict__ av,
                                    const int* __restrict__ ar,
                                    const int* __restrict__ ac,
                                    const float* __restrict__ h,
                                    float* __restrict__ out, int nnz) {
    long long gid = (long long)blockIdx.x * blockDim.x + threadIdx.x;
    int e = (int)(gid >> 7);
    if (e >= nnz) return;
    int o = (int)(gid & 127);
    atomicAdd(&out[(long long)ar[e] * O_DIM + o], av[e] * h[(long long)ac[e] * O_DIM + o]);
}

__global__ void relu_kernel(float* __restrict__ out, int n4) {
    int stride = gridDim.x * blockDim.x;
    float4* p = (float4*)out;
    for (int i = blockIdx.x * blockDim.x + threadIdx.x; i < n4; i += stride) {
        float4 v = p[i];
        v.x = fmaxf(v.x, 0.0f); v.y = fmaxf(v.y, 0.0f);
        v.z = fmaxf(v.z, 0.0f); v.w = fmaxf(v.w, 0.0f);
        p[i] = v;
    }
}

// ---------------------------------------------------------------------------
static inline size_t align256(size_t x) { return (x + 255) & ~(size_t)255; }

extern "C" void kernel_launch(void* const* d_in, const int* in_sizes, int n_in,
                              void* d_out, int out_size, void* d_ws, size_t ws_size,
                              hipStream_t stream) {
    const float* x_vals   = (const float*)d_in[0];
    const float* kern     = (const float*)d_in[1];   // [256 x 128]
    const float* adj_vals = (const float*)d_in[2];
    const int*   x_rows   = (const int*)d_in[3];
    const int*   x_cols   = (const int*)d_in[4];
    const int*   adj_rows = (const int*)d_in[5];
    const int*   adj_cols = (const int*)d_in[6];
    const void*  mask     = d_in[7];

    const int nnz_x = in_sizes[0];
    const int nnz_a = in_sizes[2];
    const int n_nodes = out_size / O_DIM;
    const int ntot = 2 * n_nodes;
    const int nbuck = (ntot + BUCK_BINS - 1) / BUCK_BINS;
    const long long nnz_tot = (long long)nnz_x + nnz_a;

    float* out = (float*)d_out;
    char* ws = (char*)d_ws;

    // ---- ws carve-up ----
    size_t off = 0;
    int* flags = (int*)d_ws;            off = align256(off + 2 * sizeof(int));
    size_t o_bcnt = off;                off = align256(off + (size_t)nbuck * 4);
    size_t o_bS = off;                  off = align256(off + ((size_t)nbuck + 1) * 4);
    size_t o_bCur = off;                off = align256(off + (size_t)nbuck * 4);
    size_t o_S = off;                   off = align256(off + ((size_t)ntot + 1) * 4);
    size_t o_rec = off;                 off = align256(off + (size_t)nnz_tot * 8);
    size_t o_packed = off;              off = align256(off + (size_t)nnz_tot * 8);
    size_t o_h = off;                   off = align256(off + (size_t)n_nodes * O_DIM * sizeof(half_t));
    const bool csr_ok = (off <= ws_size) && (nbuck <= 1024) && (n_nodes <= (1 << 17));

    // mask format detection (both paths need it)
    int scan_words = nnz_x / 4;
    if (scan_words > 16384) scan_words = 16384;
    detect_mask_kernel<<<1, 256, 0, stream>>>((const unsigned int*)mask, scan_words, flags);

    if (csr_ok) {
        int*  bcnt   = (int*)(ws + o_bcnt);
        int*  buckS  = (int*)(ws + o_bS);
        int*  buckCur= (int*)(ws + o_bCur);
        int*  S      = (int*)(ws + o_S);
        int2* rec    = (int2*)(ws + o_rec);
        int2* packed = (int2*)(ws + o_packed);
        half2_t* h2  = (half2_t*)(ws + o_h);

        hipMemsetAsync(bcnt, 0, (size_t)nbuck * 4, stream);

        // 1. coarse bucket histogram (LDS-aggregated)
        {
            int blocks = (int)((nnz_tot + 255) / 256); if (blocks > 1024) blocks = 1024;
            count_buckets_kernel<<<blocks, 256, 0, stream>>>(x_rows, nnz_x, adj_rows, nnz_a,
                                                             n_nodes, nbuck, bcnt);
        }
        // 2. bucket scan (writes buckS, cursor copy, and S sentinel)
        scan_buckets_kernel<<<1, 1024, 0, stream>>>(bcnt, nbuck, buckS, buckCur, &S[ntot]);
        // 3. phase A: frontier-local scatter into bucket regions
        {
            int blocks = (int)((nnz_tot + 255) / 256); if (blocks > 2048) blocks = 2048;
            binscat_kernel<<<blocks, 256, 0, stream>>>(x_vals, x_rows, x_cols, mask, flags,
                                                       adj_vals, adj_rows, adj_cols,
                                                       nnz_x, nnz_a, n_nodes, buckCur, rec);
        }
        // 4. phase B: per-bucket LDS counting sort -> packed + row_start S
        bucket_sort_kernel<<<nbuck, 256, 0, stream>>>(rec, buckS, ntot, packed, S);
        // 5. SpMM1: h(f16) = dropout(X) @ kernel
        {
            int blocks = (n_nodes * 64 + 255) / 256;
            spmm1_wave_kernel<<<blocks, 256, 0, stream>>>(S, packed, (const float2*)kern,
                                                          h2, n_nodes);
        }
        // 6. SpMM2 + ReLU: out = relu(adj @ h)
        {
            int blocks = (n_nodes * 64 + 255) / 256;
            spmm2_wave_kernel<<<blocks, 256, 0, stream>>>(S + n_nodes, packed, h2,
                                                          (float2*)out, n_nodes);
        }
    } else {
        // ---- fallback: atomic path ----
        float* h = (float*)(ws + 256);
        hipMemsetAsync(h, 0, (size_t)n_nodes * O_DIM * 4, stream);
        hipMemsetAsync(out, 0, (size_t)out_size * 4, stream);
        {
            long long threads = (long long)nnz_x * O_DIM;
            int blocks = (int)((threads + 255) / 256);
            spmm1_atomic_kernel<<<blocks, 256, 0, stream>>>(x_vals, x_rows, x_cols, mask,
                                                            kern, flags, h, nnz_x);
            threads = (long long)nnz_a * O_DIM;
            blocks = (int)((threads + 255) / 256);
            spmm2_atomic_kernel<<<blocks, 256, 0, stream>>>(adj_vals, adj_rows, adj_cols,
                                                            h, out, nnz_a);
        }
        int n4 = out_size / 4;
        int blocks = (n4 + 255) / 256; if (blocks > 2048) blocks = 2048;
        relu_kernel<<<blocks, 256, 0, stream>>>(out, n4);
    }
}

// Round 5
// 266.961 us; speedup vs baseline: 4.2320x; 4.2320x over previous
//
#include <hip/hip_runtime.h>
#include <hip/hip_bf16.h>

// GraphSparseConvolution on MI355X.
// Round 5: deterministic multisplit replaces the contended-atomic binscat.
//   A) tile_hist: per-8192-edge-tile LDS histogram over coarse buckets,
//      stored transposed hist[k*B+b]
//   B) 3-phase exclusive scan of the KxB matrix -> exact chunk offsets tofs
//   C) multisplit: LDS cursors seeded from tofs, LDS-atomic ranking, zero
//      global atomics, contiguous per-(tile,bucket) chunk writes
// Then per-bucket LDS counting sort (row_start S + packed records), and
// wave-per-row SpMMs with f16 h. Fallback to atomic path if ws too small.

static constexpr int O_DIM = 128;
static constexpr float KEEP_INV = 1.0f / 0.9f;  // 1/keep_prob
static constexpr int BUCK_BINS = 256;           // rows per coarse bucket
static constexpr int TILE = 8192;               // edges per multisplit tile

using half_t = _Float16;
using half2_t = _Float16 __attribute__((ext_vector_type(2)));

// ---------------------------------------------------------------------------
// Detect how the harness materialized the bool keep_mask (int32/f32/uint8).
__global__ void detect_mask_kernel(const unsigned int* __restrict__ w, int nwords,
                                   int* __restrict__ flags) {
    __shared__ int sA[256];
    __shared__ int sB[256];
    int t = threadIdx.x;
    int violA = 0, violB = 0;
    for (int i = t; i < nwords; i += 256) {
        unsigned int x = w[i];
        violA |= (x > 1u) ? 1 : 0;
        violB |= (x != 0u && x != 0x3F800000u) ? 1 : 0;
    }
    sA[t] = violA; sB[t] = violB;
    __syncthreads();
    for (int s = 128; s > 0; s >>= 1) {
        if (t < s) { sA[t] |= sA[t + s]; sB[t] |= sB[t + s]; }
        __syncthreads();
    }
    if (t == 0) { flags[0] = sA[0]; flags[1] = sB[0]; }
}

// ---------------------------------------------------------------------------
// A) per-tile bucket histogram, written transposed: histT[k*B + b].
__global__ __launch_bounds__(256) void tile_hist_kernel(
        const int* __restrict__ xr, int nnz_x,
        const int* __restrict__ ar, int nnz_a,
        int n_nodes, int nbuck, int B,
        int* __restrict__ histT) {
    __shared__ int hist[1024];
    int b = blockIdx.x, t = threadIdx.x;
    for (int k = t; k < nbuck; k += 256) hist[k] = 0;
    __syncthreads();
    int tot = nnz_x + nnz_a;
    int tstart = b * TILE;
    int tend = min(tstart + TILE, tot);
    for (int i = tstart + t; i < tend; i += 256) {
        int bin = (i < nnz_x) ? xr[i] : (n_nodes + ar[i - nnz_x]);
        atomicAdd(&hist[bin >> 8], 1);
    }
    __syncthreads();
    for (int k = t; k < nbuck; k += 256)
        histT[(size_t)k * B + b] = hist[k];
}

// ---------------------------------------------------------------------------
// 3-phase exclusive scan over cnt[0..n) -> S[0..n).
static constexpr int SCAN_BS = 256;
static constexpr int SCAN_IPT = 8;
static constexpr int SCAN_CHUNK = SCAN_BS * SCAN_IPT;  // 2048

__global__ __launch_bounds__(SCAN_BS) void scan_partial_kernel(const int* __restrict__ cnt,
                                                               int n, int* __restrict__ bsums) {
    int b = blockIdx.x, t = threadIdx.x;
    int lane = t & 63, wid = t >> 6;
    __shared__ int wsum[SCAN_BS / 64];
    int base = b * SCAN_CHUNK + t * SCAN_IPT;
    int s = 0;
    #pragma unroll
    for (int k = 0; k < SCAN_IPT; ++k) {
        int i = base + k;
        s += (i < n) ? cnt[i] : 0;
    }
    #pragma unroll
    for (int d = 1; d < 64; d <<= 1) s += __shfl_xor(s, d, 64);
    if (lane == 0) wsum[wid] = s;
    __syncthreads();
    if (t == 0) {
        int tot = 0;
        #pragma unroll
        for (int w = 0; w < SCAN_BS / 64; ++w) tot += wsum[w];
        bsums[b] = tot;
    }
}

// Single block: exclusive-scan bsums[0..nb) in place; write grand total to
// two sentinel locations (tofs[n_scan] and S[ntot]).
__global__ __launch_bounds__(1024) void scan_blocksums_kernel(int* __restrict__ bsums, int nb,
                                                              int* __restrict__ sent0,
                                                              int* __restrict__ sent1) {
    __shared__ int wsum[16];
    int t = threadIdx.x, lane = t & 63, wid = t >> 6;
    int v = (t < nb) ? bsums[t] : 0;
    int s = v;
    #pragma unroll
    for (int d = 1; d < 64; d <<= 1) {
        int u = __shfl_up(s, d, 64);
        if (lane >= d) s += u;
    }
    if (lane == 63) wsum[wid] = s;
    __syncthreads();
    int woff = 0;
    for (int w = 0; w < wid; ++w) woff += wsum[w];
    if (t < nb) bsums[t] = woff + s - v;      // exclusive
    if (t == 1023) { int tot = woff + s; *sent0 = tot; *sent1 = tot; }
}

__global__ __launch_bounds__(SCAN_BS) void scan_final_kernel(const int* __restrict__ cnt, int n,
                                                             const int* __restrict__ bsums,
                                                             int* __restrict__ S) {
    __shared__ int wsum[SCAN_BS / 64];
    int b = blockIdx.x, t = threadIdx.x;
    int lane = t & 63, wid = t >> 6;
    int base = b * SCAN_CHUNK + t * SCAN_IPT;
    int v[SCAN_IPT];
    int tsum = 0;
    #pragma unroll
    for (int k = 0; k < SCAN_IPT; ++k) {
        int i = base + k;
        v[k] = (i < n) ? cnt[i] : 0;
        tsum += v[k];
    }
    int s = tsum;
    #pragma unroll
    for (int d = 1; d < 64; d <<= 1) {
        int u = __shfl_up(s, d, 64);
        if (lane >= d) s += u;
    }
    if (lane == 63) wsum[wid] = s;
    __syncthreads();
    int woff = 0;
    for (int w = 0; w < wid; ++w) woff += wsum[w];
    int excl = bsums[b] + woff + (s - tsum);
    #pragma unroll
    for (int k = 0; k < SCAN_IPT; ++k) {
        int i = base + k;
        if (i < n) S[i] = excl;
        excl += v[k];
    }
}

// ---------------------------------------------------------------------------
// C) multisplit: deterministic placement via LDS cursors seeded from tofs.
// Record: { key = (bin_local << 17) | col , val_bits }, col < 2^17.
__global__ __launch_bounds__(256) void multisplit_kernel(
        const float* __restrict__ xv,
        const int* __restrict__ xr,
        const int* __restrict__ xc,
        const void* __restrict__ mask,
        const int* __restrict__ flags,
        const float* __restrict__ av,
        const int* __restrict__ ar,
        const int* __restrict__ ac,
        int nnz_x, int nnz_a, int n_nodes,
        int nbuck, int B,
        const int* __restrict__ tofs,
        int2* __restrict__ rec) {
    __shared__ int cur[1024];
    int b = blockIdx.x, t = threadIdx.x;
    for (int k = t; k < nbuck; k += 256)
        cur[k] = tofs[(size_t)k * B + b];
    __syncthreads();
    int tot = nnz_x + nnz_a;
    int tstart = b * TILE;
    int tend = min(tstart + TILE, tot);
    int f0 = flags[0], f1 = flags[1];
    for (int i = tstart + t; i < tend; i += 256) {
        int bin, col; float v;
        if (i < nnz_x) {
            bin = xr[i];
            col = xc[i];
            bool keep;
            if (f0 == 0)      keep = ((const int*)mask)[i] != 0;
            else if (f1 == 0) keep = ((const float*)mask)[i] != 0.0f;
            else              keep = ((const unsigned char*)mask)[i] != 0;
            v = keep ? xv[i] * KEEP_INV : 0.0f;
        } else {
            int e = i - nnz_x;
            bin = n_nodes + ar[e];
            col = ac[e];
            v = av[e];
        }
        int key = ((bin & (BUCK_BINS - 1)) << 17) | col;
        int pos = atomicAdd(&cur[bin >> 8], 1);   // LDS atomic — cheap
        rec[pos] = make_int2(key, __float_as_int(v));
    }
}

// ---------------------------------------------------------------------------
// Phase B: one block per bucket.  LDS counting sort over 256 local bins:
// hist -> scan (writes row_start S) -> rank & emit sorted (col,val) records.
// Bucket bounds come from tofs (start = tofs[bb*B], end = tofs[(bb+1)*B];
// tofs[nbuck*B] is the grand-total sentinel).
__global__ __launch_bounds__(256) void bucket_sort_kernel(
        const int2* __restrict__ rec,
        const int* __restrict__ tofs, int B,
        int ntot, int2* __restrict__ packed,
        int* __restrict__ S) {
    __shared__ int hist[256];
    __shared__ int cur[256];
    __shared__ int wsum[4];
    int bb = blockIdx.x, t = threadIdx.x;
    int start = tofs[(size_t)bb * B];
    int end   = tofs[(size_t)(bb + 1) * B];
    hist[t] = 0;
    __syncthreads();
    for (int i = start + t; i < end; i += 256) {
        unsigned k = (unsigned)rec[i].x;
        atomicAdd(&hist[k >> 17], 1);
    }
    __syncthreads();
    int v = hist[t];
    int lane = t & 63, wid = t >> 6;
    int s = v;
    #pragma unroll
    for (int d = 1; d < 64; d <<= 1) {
        int u = __shfl_up(s, d, 64);
        if (lane >= d) s += u;
    }
    if (lane == 63) wsum[wid] = s;
    __syncthreads();
    int woff = 0;
    for (int w = 0; w < wid; ++w) woff += wsum[w];
    int excl = woff + s - v;
    int binBase = bb << 8;
    if (binBase + t < ntot) S[binBase + t] = start + excl;
    cur[t] = start + excl;
    __syncthreads();
    for (int i = start + t; i < end; i += 256) {
        int2 e = rec[i];
        unsigned k = (unsigned)e.x;
        int pos = atomicAdd(&cur[k >> 17], 1);
        packed[pos] = make_int2((int)(k & 0x1FFFFu), e.y);
    }
}

// ---------------------------------------------------------------------------
// SpMM1: wave-per-row, 2 cols/lane, 4 gathers in flight. src = kernel (f32),
// dst = h (f16x2).
__global__ __launch_bounds__(256) void spmm1_wave_kernel(
        const int* __restrict__ S, const int2* __restrict__ packed,
        const float2* __restrict__ kern2, half2_t* __restrict__ h2,
        int n_rows) {
    int gid = blockIdx.x * 256 + threadIdx.x;
    int r = gid >> 6;
    if (r >= n_rows) return;
    int lane = gid & 63;
    int j = S[r], end = S[r + 1];
    float ax = 0.0f, ay = 0.0f;
    for (; j + 4 <= end; j += 4) {
        int2 e0 = packed[j], e1 = packed[j + 1], e2 = packed[j + 2], e3 = packed[j + 3];
        float2 w0 = kern2[e0.x * 64 + lane];
        float2 w1 = kern2[e1.x * 64 + lane];
        float2 w2 = kern2[e2.x * 64 + lane];
        float2 w3 = kern2[e3.x * 64 + lane];
        float v0 = __int_as_float(e0.y), v1 = __int_as_float(e1.y);
        float v2 = __int_as_float(e2.y), v3 = __int_as_float(e3.y);
        ax = fmaf(v0, w0.x, ax); ay = fmaf(v0, w0.y, ay);
        ax = fmaf(v1, w1.x, ax); ay = fmaf(v1, w1.y, ay);
        ax = fmaf(v2, w2.x, ax); ay = fmaf(v2, w2.y, ay);
        ax = fmaf(v3, w3.x, ax); ay = fmaf(v3, w3.y, ay);
    }
    for (; j < end; ++j) {
        int2 e = packed[j];
        float2 w = kern2[e.x * 64 + lane];
        float v = __int_as_float(e.y);
        ax = fmaf(v, w.x, ax); ay = fmaf(v, w.y, ay);
    }
    half2_t o; o.x = (half_t)ax; o.y = (half_t)ay;
    h2[r * 64 + lane] = o;
}

// SpMM2 + ReLU: wave-per-row, src = h (f16x2), dst = out (f32x2).
__global__ __launch_bounds__(256) void spmm2_wave_kernel(
        const int* __restrict__ S, const int2* __restrict__ packed,
        const half2_t* __restrict__ h2, float2* __restrict__ out2,
        int n_rows) {
    int gid = blockIdx.x * 256 + threadIdx.x;
    int r = gid >> 6;
    if (r >= n_rows) return;
    int lane = gid & 63;
    int j = S[r], end = S[r + 1];
    float ax = 0.0f, ay = 0.0f;
    for (; j + 4 <= end; j += 4) {
        int2 e0 = packed[j], e1 = packed[j + 1], e2 = packed[j + 2], e3 = packed[j + 3];
        half2_t w0 = h2[e0.x * 64 + lane];
        half2_t w1 = h2[e1.x * 64 + lane];
        half2_t w2 = h2[e2.x * 64 + lane];
        half2_t w3 = h2[e3.x * 64 + lane];
        float v0 = __int_as_float(e0.y), v1 = __int_as_float(e1.y);
        float v2 = __int_as_float(e2.y), v3 = __int_as_float(e3.y);
        ax = fmaf(v0, (float)w0.x, ax); ay = fmaf(v0, (float)w0.y, ay);
        ax = fmaf(v1, (float)w1.x, ax); ay = fmaf(v1, (float)w1.y, ay);
        ax = fmaf(v2, (float)w2.x, ax); ay = fmaf(v2, (float)w2.y, ay);
        ax = fmaf(v3, (float)w3.x, ax); ay = fmaf(v3, (float)w3.y, ay);
    }
    for (; j < end; ++j) {
        int2 e = packed[j];
        half2_t w = h2[e.x * 64 + lane];
        float v = __int_as_float(e.y);
        ax = fmaf(v, (float)w.x, ax); ay = fmaf(v, (float)w.y, ay);
    }
    out2[r * 64 + lane] = make_float2(fmaxf(ax, 0.0f), fmaxf(ay, 0.0f));
}

// ---------------------------------------------------------------------------
// Fallback atomic path (only if ws too small).
__global__ void spmm1_atomic_kernel(const float* __restrict__ xv,
                                    const int* __restrict__ xr,
                                    const int* __restrict__ xc,
                                    const void* __restrict__ mask,
                                    const float* __restrict__ kern,
                                    const int* __restrict__ flags,
                                    float* __restrict__ h, int nnz) {
    long long gid = (long long)blockIdx.x * blockDim.x + threadIdx.x;
    int e = (int)(gid >> 7);
    if (e >= nnz) return;
    int o = (int)(gid & 127);
    bool keep;
    if (flags[0] == 0)      keep = ((const int*)mask)[e] != 0;
    else if (flags[1] == 0) keep = ((const float*)mask)[e] != 0.0f;
    else                    keep = ((const unsigned char*)mask)[e] != 0;
    if (!keep) return;
    atomicAdd(&h[(long long)xr[e] * O_DIM + o], xv[e] * KEEP_INV * kern[xc[e] * O_DIM + o]);
}

__global__ void spmm2_atomic_kernel(const float* __restrict__ av,
                                    const int* __restrict__ ar,
                                    const int* __restrict__ ac,
                                    const float* __restrict__ h,
                                    float* __restrict__ out, int nnz) {
    long long gid = (long long)blockIdx.x * blockDim.x + threadIdx.x;
    int e = (int)(gid >> 7);
    if (e >= nnz) return;
    int o = (int)(gid & 127);
    atomicAdd(&out[(long long)ar[e] * O_DIM + o], av[e] * h[(long long)ac[e] * O_DIM + o]);
}

__global__ void relu_kernel(float* __restrict__ out, int n4) {
    int stride = gridDim.x * blockDim.x;
    float4* p = (float4*)out;
    for (int i = blockIdx.x * blockDim.x + threadIdx.x; i < n4; i += stride) {
        float4 v = p[i];
        v.x = fmaxf(v.x, 0.0f); v.y = fmaxf(v.y, 0.0f);
        v.z = fmaxf(v.z, 0.0f); v.w = fmaxf(v.w, 0.0f);
        p[i] = v;
    }
}

// ---------------------------------------------------------------------------
static inline size_t align256(size_t x) { return (x + 255) & ~(size_t)255; }

extern "C" void kernel_launch(void* const* d_in, const int* in_sizes, int n_in,
                              void* d_out, int out_size, void* d_ws, size_t ws_size,
                              hipStream_t stream) {
    const float* x_vals   = (const float*)d_in[0];
    const float* kern     = (const float*)d_in[1];   // [256 x 128]
    const float* adj_vals = (const float*)d_in[2];
    const int*   x_rows   = (const int*)d_in[3];
    const int*   x_cols   = (const int*)d_in[4];
    const int*   adj_rows = (const int*)d_in[5];
    const int*   adj_cols = (const int*)d_in[6];
    const void*  mask     = d_in[7];

    const int nnz_x = in_sizes[0];
    const int nnz_a = in_sizes[2];
    const int n_nodes = out_size / O_DIM;
    const int ntot = 2 * n_nodes;
    const int nbuck = (ntot + BUCK_BINS - 1) / BUCK_BINS;
    const long long nnz_tot = (long long)nnz_x + nnz_a;
    const int B = (int)((nnz_tot + TILE - 1) / TILE);           // tiles
    const long long n_scan = (long long)nbuck * B;              // KxB matrix
    const int nb_scan = (int)((n_scan + SCAN_CHUNK - 1) / SCAN_CHUNK);

    float* out = (float*)d_out;
    char* ws = (char*)d_ws;

    // ---- ws carve-up ----
    size_t off = 0;
    int* flags = (int*)d_ws;            off = align256(off + 2 * sizeof(int));
    size_t o_histT = off;               off = align256(off + (size_t)n_scan * 4);
    size_t o_tofs = off;                off = align256(off + ((size_t)n_scan + 1) * 4);
    size_t o_bsums = off;               off = align256(off + 4096 * 4);
    size_t o_S = off;                   off = align256(off + ((size_t)ntot + 1) * 4);
    size_t o_rec = off;                 off = align256(off + (size_t)nnz_tot * 8);
    size_t o_packed = off;              off = align256(off + (size_t)nnz_tot * 8);
    size_t o_h = off;                   off = align256(off + (size_t)n_nodes * O_DIM * sizeof(half_t));
    const bool csr_ok = (off <= ws_size) && (nbuck <= 1024) &&
                        (n_nodes <= (1 << 17)) && (nb_scan <= 1024);

    // mask format detection (both paths need it)
    int scan_words = nnz_x / 4;
    if (scan_words > 16384) scan_words = 16384;
    detect_mask_kernel<<<1, 256, 0, stream>>>((const unsigned int*)mask, scan_words, flags);

    if (csr_ok) {
        int*  histT  = (int*)(ws + o_histT);
        int*  tofs   = (int*)(ws + o_tofs);
        int*  bsums  = (int*)(ws + o_bsums);
        int*  S      = (int*)(ws + o_S);
        int2* rec    = (int2*)(ws + o_rec);
        int2* packed = (int2*)(ws + o_packed);
        half2_t* h2  = (half2_t*)(ws + o_h);

        // A) per-tile bucket histograms (transposed)
        tile_hist_kernel<<<B, 256, 0, stream>>>(x_rows, nnz_x, adj_rows, nnz_a,
                                                n_nodes, nbuck, B, histT);
        // B) exclusive scan of the KxB matrix -> exact chunk offsets
        scan_partial_kernel<<<nb_scan, SCAN_BS, 0, stream>>>(histT, (int)n_scan, bsums);
        scan_blocksums_kernel<<<1, 1024, 0, stream>>>(bsums, nb_scan,
                                                      &tofs[n_scan], &S[ntot]);
        scan_final_kernel<<<nb_scan, SCAN_BS, 0, stream>>>(histT, (int)n_scan, bsums, tofs);
        // C) multisplit: deterministic scatter, LDS-atomic ranking only
        multisplit_kernel<<<B, 256, 0, stream>>>(x_vals, x_rows, x_cols, mask, flags,
                                                 adj_vals, adj_rows, adj_cols,
                                                 nnz_x, nnz_a, n_nodes, nbuck, B,
                                                 tofs, rec);
        // D) per-bucket LDS counting sort -> packed + row_start S
        bucket_sort_kernel<<<nbuck, 256, 0, stream>>>(rec, tofs, B, ntot, packed, S);
        // E) SpMM1: h(f16) = dropout(X) @ kernel
        {
            int blocks = (n_nodes * 64 + 255) / 256;
            spmm1_wave_kernel<<<blocks, 256, 0, stream>>>(S, packed, (const float2*)kern,
                                                          h2, n_nodes);
        }
        // F) SpMM2 + ReLU: out = relu(adj @ h)
        {
            int blocks = (n_nodes * 64 + 255) / 256;
            spmm2_wave_kernel<<<blocks, 256, 0, stream>>>(S + n_nodes, packed, h2,
                                                          (float2*)out, n_nodes);
        }
    } else {
        // ---- fallback: atomic path ----
        float* h = (float*)(ws + 256);
        hipMemsetAsync(h, 0, (size_t)n_nodes * O_DIM * 4, stream);
        hipMemsetAsync(out, 0, (size_t)out_size * 4, stream);
        {
            long long threads = (long long)nnz_x * O_DIM;
            int blocks = (int)((threads + 255) / 256);
            spmm1_atomic_kernel<<<blocks, 256, 0, stream>>>(x_vals, x_rows, x_cols, mask,
                                                            kern, flags, h, nnz_x);
            threads = (long long)nnz_a * O_DIM;
            blocks = (int)((threads + 255) / 256);
            spmm2_atomic_kernel<<<blocks, 256, 0, stream>>>(adj_vals, adj_rows, adj_cols,
                                                            h, out, nnz_a);
        }
        int n4 = out_size / 4;
        int blocks = (n4 + 255) / 256; if (blocks > 2048) blocks = 2048;
        relu_kernel<<<blocks, 256, 0, stream>>>(out, n4);
    }
}